// Round 9
// baseline (53.205 us; speedup 1.0000x reference)
//
#include <hip/hip_runtime.h>
#include <hip/hip_bf16.h>

// Problem constants (match reference setup_inputs)
#define B 256
#define L 512
#define H 256
#define K 512
#define RELV 50000          // rel_emb rows
#define BM 32               // rel rows per GEMM block
#define NBINS 1563          // ceil(RELV/BM), 1 bucket per GEMM block
#define CAP 256             // bucket capacity (mean 84, Poisson tail ~e^-113)

// ws layout (bytes):
//   [0, 131072)        : ushort encfrag[16][8][64][8]  enc bf16, MFMA-frag order
//   [262144, 270336)   : int ws_cnt[NBINS]             (memset 0 each launch)
//   [270336, ...)      : uint2 ws_ent[NBINS][CAP]      {out_idx, row} (3.2 MB)
#define WS_ENC_OFF 0
#define WS_CNT_OFF 262144
#define WS_ENT_OFF 270336
#define WS_NEEDED  (WS_ENT_OFF + (size_t)NBINS * CAP * 8)

typedef __attribute__((ext_vector_type(8))) short bf16x8;
typedef __attribute__((ext_vector_type(4))) float f32x4;

__device__ __forceinline__ ushort f2bf(float f) {
    unsigned u = __float_as_uint(f);
    u += 0x7fffu + ((u >> 16) & 1u);      // round-to-nearest-even
    return (ushort)(u >> 16);
}

__device__ __forceinline__ unsigned pk2(float x, float y) {
    union { __hip_bfloat162 h; unsigned u; } cv;
    cv.h = __float22bfloat162_rn(make_float2(x, y));   // v_cvt_pk_bf16_f32
    return cv.u;
}

// ---- kernel 1 (grid 512): bin the 131072 (out_idx,row) pairs by row>>5,
//      and (blocks 0..255) build the enc bf16 fragment table ----
__global__ __launch_bounds__(256)
void bin_and_enc(const int* __restrict__ entities,
                 const int* __restrict__ actions,
                 const int* __restrict__ action_keys,
                 const float* __restrict__ encoded,
                 ushort* __restrict__ encfrag,
                 int* __restrict__ ws_cnt,
                 uint2* __restrict__ ws_ent)
{
    const int blk = blockIdx.x, t = threadIdx.x, lane = t & 63;
    const int tid = blk * 256 + t;               // out_idx = b*K + k

    // ---- binning ----
    const int r   = actions[action_keys[tid]];
    const int bin = r >> 5;                      // BM == 32
    const int pos = atomicAdd(&ws_cnt[bin], 1);
    if (pos < CAP) ws_ent[bin * CAP + pos] = make_uint2((unsigned)tid, (unsigned)r);

    // ---- enc_last -> fragment-order bf16 table (blocks 0..255 only) ----
    if (blk < B) {
        const int b = blk;
        __shared__ int s_count;
        if (t == 0) s_count = 0;
        __syncthreads();
        unsigned long long m0 = __ballot(entities[b * L + t] != 0);
        unsigned long long m1 = __ballot(entities[b * L + t + 256] != 0);
        if (lane == 0) atomicAdd(&s_count, __popcll(m0) + __popcll(m1));
        __syncthreads();
        int idx = s_count - 1;
        idx = max(0, min(L - 1, idx));           // matches JAX clip-mode gather

        const int h = t;
        const ushort val = f2bf(encoded[((size_t)(b * L + idx)) * H + h]);
        const int ct = b >> 4;
        const int kb = h >> 5;
        const int hi = (h >> 3) & 3;
        const int e  = h & 7;
        const int lf = (b & 15) | (hi << 4);
        encfrag[((((ct * 8 + kb) * 64) + lf) << 3) | e] = val;
    }
}

// ---- kernel 2 (grid NBINS): 32x256 MFMA tile + in-block scatter epilogue ----
// A staged via XOR-swizzled LDS; B-frags coalesced from encfrag (L2-hot).
// MFMA fragment mappings bench-verified R6-R8 (absmax 7.8e-3 passes).
__global__ __launch_bounds__(256)
void gemm_fused(const float* __restrict__ rel_emb,
                const ushort* __restrict__ encfrag,
                const int* __restrict__ ws_cnt,
                const uint2* __restrict__ ws_ent,
                float* __restrict__ out)
{
    __shared__ __align__(16) char smem[BM * 256 * 4];   // 32 KB
    ushort* As = (ushort*)smem;                         // bf16 A tile (16 KB)
    float*  Ls = (float*)smem;                          // f32 result tile (32 KB)

    const int t    = threadIdx.x;
    const int lane = t & 63;
    const int w    = t >> 6;
    const int bid  = blockIdx.x;
    const int r0   = bid * BM;

    // ---- stage A: 4 iters, coalesced 1 KB-per-row loads, cvt, swizzled write ----
    #pragma unroll
    for (int it = 0; it < 4; ++it) {
        const int row = it * 8 + (t >> 5);          // 0..31
        const int kc  = (t & 31) * 8;               // 0..248
        const int arow = min(r0 + row, RELV - 1);   // tail clamp (loads only)
        const float4 a0 = *(const float4*)&rel_emb[(size_t)arow * H + kc];
        const float4 a1 = *(const float4*)&rel_emb[(size_t)arow * H + kc + 4];
        union { bf16x8 v; unsigned u[4]; } af;
        af.u[0] = pk2(a0.x, a0.y);
        af.u[1] = pk2(a0.z, a0.w);
        af.u[2] = pk2(a1.x, a1.y);
        af.u[3] = pk2(a1.z, a1.w);
        const int us = row * 256 + (((kc * 2) ^ ((row & 7) << 4)) >> 1);
        *(bf16x8*)&As[us] = af.v;
    }
    __syncthreads();

    // ---- compute: acc[strip][cf] over kb=0..7 ----
    const int lrow = lane & 15;    // A row / B col / D col within 16
    const int lkb  = lane >> 4;    // k sub-block (8 elems)
    const int colbase = w * 64;
    const int ct0 = colbase >> 4;

    f32x4 acc[2][4];
    #pragma unroll
    for (int s = 0; s < 2; ++s)
        #pragma unroll
        for (int c = 0; c < 4; ++c)
            acc[s][c] = (f32x4){0.f, 0.f, 0.f, 0.f};

    #pragma unroll
    for (int kb = 0; kb < 8; ++kb) {
        bf16x8 Bf0 = *(const bf16x8*)&encfrag[(((ct0 + 0) * 8 + kb) * 64 + lane) * 8];
        bf16x8 Bf1 = *(const bf16x8*)&encfrag[(((ct0 + 1) * 8 + kb) * 64 + lane) * 8];
        bf16x8 Bf2 = *(const bf16x8*)&encfrag[(((ct0 + 2) * 8 + kb) * 64 + lane) * 8];
        bf16x8 Bf3 = *(const bf16x8*)&encfrag[(((ct0 + 3) * 8 + kb) * 64 + lane) * 8];

        #pragma unroll
        for (int s = 0; s < 2; ++s) {
            const int row = s * 16 + lrow;
            const int kbyte = (kb * 64 + lkb * 16) ^ ((lrow & 7) << 4);
            const bf16x8 a = *(const bf16x8*)&As[row * 256 + (kbyte >> 1)];
            acc[s][0] = __builtin_amdgcn_mfma_f32_16x16x32_bf16(a, Bf0, acc[s][0], 0, 0, 0);
            acc[s][1] = __builtin_amdgcn_mfma_f32_16x16x32_bf16(a, Bf1, acc[s][1], 0, 0, 0);
            acc[s][2] = __builtin_amdgcn_mfma_f32_16x16x32_bf16(a, Bf2, acc[s][2], 0, 0, 0);
            acc[s][3] = __builtin_amdgcn_mfma_f32_16x16x32_bf16(a, Bf3, acc[s][3], 0, 0, 0);
        }
    }
    __syncthreads();   // all As reads done; smem becomes Ls

    // ---- acc -> LDS f32 tile: D col = lane&15, row = lkb*4+j (verified) ----
    #pragma unroll
    for (int s = 0; s < 2; ++s) {
        const int lr = s * 16 + lkb * 4;
        #pragma unroll
        for (int c = 0; c < 4; ++c) {
            const int col = colbase + c * 16 + lrow;
            #pragma unroll
            for (int j = 0; j < 4; ++j)
                Ls[(lr + j) * 256 + col] = acc[s][c][j];
        }
    }
    __syncthreads();

    // ---- consume this block's bucket: out[e.x] = Ls[(e.y-r0)*256 + b] ----
    const int cnt = min(ws_cnt[bid], CAP);
    for (int i = t; i < cnt; i += 256) {
        const uint2 e = ws_ent[(size_t)bid * CAP + i];
        const int b  = (int)(e.x >> 9);          // out_idx / K
        const int lr = (int)(e.y & (BM - 1));    // row within tile
        out[e.x] = Ls[lr * 256 + b];
    }
}

// ---- fallback (proven R2 kernel) if ws too small ----
#define CHUNKS 8
#define KPB (K / CHUNKS)
#define KPW (KPB / 4)
#define KPG (KPW / 4)

__global__ __launch_bounds__(256)
void preds_fused_kernel(const int* __restrict__ entities,
                        const int* __restrict__ actions,
                        const int* __restrict__ action_keys,
                        const float* __restrict__ encoded,
                        const float* __restrict__ rel_emb,
                        float* __restrict__ out)
{
    const int blk   = blockIdx.x;
    const int b     = blk >> 3;
    const int chunk = blk & 7;
    const int t     = threadIdx.x;
    const int lane  = t & 63;
    const int wave  = t >> 6;
    const int gid   = lane >> 4;
    const int gl    = lane & 15;

    __shared__ int s_count;
    if (t == 0) s_count = 0;
    __syncthreads();
    unsigned long long m0 = __ballot(entities[b * L + t] != 0);
    unsigned long long m1 = __ballot(entities[b * L + t + 256] != 0);
    if (lane == 0) atomicAdd(&s_count, __popcll(m0) + __popcll(m1));
    __syncthreads();
    int idx = s_count - 1;
    idx = max(0, min(L - 1, idx));

    const int kw = chunk * KPB + wave * KPW;
    const int* ak = action_keys + b * K;
    int av = 0;
    if (lane < KPW) av = actions[ak[kw + lane]];

    const float* encrow = &encoded[((size_t)(b * L + idx)) * H];
    const float4 e0 = *(const float4*)&encrow[gl * 4];
    const float4 e1 = *(const float4*)&encrow[gl * 4 + 64];
    const float4 e2 = *(const float4*)&encrow[gl * 4 + 128];
    const float4 e3 = *(const float4*)&encrow[gl * 4 + 192];

    #pragma unroll
    for (int i = 0; i < KPG; i += 2) {
        const int o0 = gid * KPG + i;
        const int o1 = o0 + 1;
        const int a0 = __shfl(av, o0, 64);
        const int a1 = __shfl(av, o1, 64);
        const float* r0 = &rel_emb[(size_t)a0 * H];
        const float* r1 = &rel_emb[(size_t)a1 * H];

        float4 r00 = *(const float4*)&r0[gl * 4];
        float4 r01 = *(const float4*)&r0[gl * 4 + 64];
        float4 r02 = *(const float4*)&r0[gl * 4 + 128];
        float4 r03 = *(const float4*)&r0[gl * 4 + 192];
        float4 r10 = *(const float4*)&r1[gl * 4];
        float4 r11 = *(const float4*)&r1[gl * 4 + 64];
        float4 r12 = *(const float4*)&r1[gl * 4 + 128];
        float4 r13 = *(const float4*)&r1[gl * 4 + 192];

        float p0 = r00.x * e0.x + r00.y * e0.y + r00.z * e0.z + r00.w * e0.w;
        p0 += r01.x * e1.x + r01.y * e1.y + r01.z * e1.z + r01.w * e1.w;
        p0 += r02.x * e2.x + r02.y * e2.y + r02.z * e2.z + r02.w * e2.w;
        p0 += r03.x * e3.x + r03.y * e3.y + r03.z * e3.z + r03.w * e3.w;
        float p1 = r10.x * e0.x + r10.y * e0.y + r10.z * e0.z + r10.w * e0.w;
        p1 += r11.x * e1.x + r11.y * e1.y + r11.z * e1.z + r11.w * e1.w;
        p1 += r12.x * e2.x + r12.y * e2.y + r12.z * e2.z + r12.w * e2.w;
        p1 += r13.x * e3.x + r13.y * e3.y + r13.z * e3.z + r13.w * e3.w;

        #pragma unroll
        for (int off = 1; off < 16; off <<= 1) {
            p0 += __shfl_xor(p0, off, 64);
            p1 += __shfl_xor(p1, off, 64);
        }
        if (gl == 0) {
            out[b * K + kw + o0] = p0;
            out[b * K + kw + o1] = p1;
        }
    }
}

extern "C" void kernel_launch(void* const* d_in, const int* in_sizes, int n_in,
                              void* d_out, int out_size, void* d_ws, size_t ws_size,
                              hipStream_t stream)
{
    const int*   entities    = (const int*)d_in[0];
    // d_in[1] = relations (unused by the reference computation)
    const int*   actions     = (const int*)d_in[2];
    const int*   action_keys = (const int*)d_in[3];
    const float* encoded     = (const float*)d_in[4];
    const float* rel_emb     = (const float*)d_in[5];
    float*       out         = (float*)d_out;

    if (ws_size >= WS_NEEDED) {
        ushort* encfrag = (ushort*)((char*)d_ws + WS_ENC_OFF);
        int*    ws_cnt  = (int*)((char*)d_ws + WS_CNT_OFF);
        uint2*  ws_ent  = (uint2*)((char*)d_ws + WS_ENT_OFF);

        hipMemsetAsync(ws_cnt, 0, NBINS * sizeof(int), stream);
        hipLaunchKernelGGL(bin_and_enc, dim3(B * K / 256), dim3(256), 0, stream,
                           entities, actions, action_keys, encoded,
                           encfrag, ws_cnt, ws_ent);
        hipLaunchKernelGGL(gemm_fused, dim3(NBINS), dim3(256), 0, stream,
                           rel_emb, encfrag, ws_cnt, ws_ent, out);
    } else {
        hipLaunchKernelGGL(preds_fused_kernel, dim3(B * CHUNKS), dim3(256), 0, stream,
                           entities, actions, action_keys, encoded, rel_emb, out);
    }
}

// Round 10
// 34.527 us; speedup vs baseline: 1.5410x; 1.5410x over previous
//
#include <hip/hip_runtime.h>
#include <hip/hip_bf16.h>

// Problem constants (match reference setup_inputs)
#define B 256
#define L 512
#define H 256
#define K 512
#define RELV 50000          // rel_emb rows
#define BM 32               // rel rows per GEMM block -> 1563 blocks (~6/CU)

// ws layout (bytes):
//   [0, 131072)     : ushort encfrag[16][8][64][8]  enc_last bf16 in MFMA-fragment
//                     order: [ct][kb][lane][e] = enc[col=16ct+(lane&15)][k=kb*32+(lane>>4)*8+e]
//   [262144, ...)   : ushort P2[RELV][B]            bf16 scores, row-major (25.6 MB)
#define WS_ENC_OFF 0
#define WS_P2_OFF  (256 * 1024)
#define WS_NEEDED  (WS_P2_OFF + (size_t)RELV * B * 2)

typedef __attribute__((ext_vector_type(8))) short bf16x8;
typedef __attribute__((ext_vector_type(4))) float f32x4;

__device__ __forceinline__ ushort f2bf(float f) {
    unsigned u = __float_as_uint(f);
    u += 0x7fffu + ((u >> 16) & 1u);      // round-to-nearest-even
    return (ushort)(u >> 16);
}

// single-instruction packed cast: v_cvt_pk_bf16_f32 (gfx950)
__device__ __forceinline__ unsigned pk2(float x, float y) {
    union { __hip_bfloat162 h; unsigned u; } cv;
    cv.h = __float22bfloat162_rn(make_float2(x, y));   // .x -> low16, .y -> high16
    return cv.u;
}

// ---- kernel 1: last-non-pad gather + bf16 cast into fragment-order table ----
__global__ __launch_bounds__(256)
void enc_cast(const int* __restrict__ entities,
              const float* __restrict__ encoded,
              ushort* __restrict__ encfrag)
{
    const int b = blockIdx.x, t = threadIdx.x, lane = t & 63;
    __shared__ int s_count;
    if (t == 0) s_count = 0;
    __syncthreads();
    unsigned long long m0 = __ballot(entities[b * L + t] != 0);
    unsigned long long m1 = __ballot(entities[b * L + t + 256] != 0);
    if (lane == 0) atomicAdd(&s_count, __popcll(m0) + __popcll(m1));
    __syncthreads();
    int idx = s_count - 1;
    idx = max(0, min(L - 1, idx));        // matches JAX clip-mode gather

    const int h = t;
    const ushort val = f2bf(encoded[((size_t)(b * L + idx)) * H + h]);
    // fragment-order address
    const int ct = b >> 4;
    const int kb = h >> 5;
    const int hi = (h >> 3) & 3;
    const int e  = h & 7;
    const int lf = (b & 15) | (hi << 4);
    encfrag[((((ct * 8 + kb) * 64) + lf) << 3) | e] = val;
}

// ---- kernel 2: P2[r][b] = rel_emb[r] . enc_last[b], LDS-staged bf16 MFMA GEMM
// block = 4 waves, BM = 32 rel rows, BN = 256 (wave w owns cols w*64..+63), K = 256.
// Stage: ALL global loads hoisted into registers first (128 B/thread in flight),
// then cvt + swizzled ds_write. MFMA fragment mappings bench-verified R6-R9.
__global__ __launch_bounds__(256)
void gemm_p2(const float* __restrict__ rel_emb,
             const ushort* __restrict__ encfrag,
             ushort* __restrict__ P2)
{
    __shared__ ushort As[BM * 256];        // 16 KB bf16 A-tile, swizzled rows

    const int t    = threadIdx.x;
    const int lane = t & 63;
    const int w    = t >> 6;
    const int r0   = blockIdx.x * BM;

    // ---- stage A: load ALL 8 float4 first (max MLP), then convert+write ----
    const int kc = (t & 31) * 8;                    // 0..248
    float4 La[4][2];
    #pragma unroll
    for (int it = 0; it < 4; ++it) {
        const int row  = it * 8 + (t >> 5);         // 0..31
        const int arow = min(r0 + row, RELV - 1);   // tail clamp (loads only)
        const float* ap = &rel_emb[(size_t)arow * H + kc];
        La[it][0] = *(const float4*)(ap);
        La[it][1] = *(const float4*)(ap + 4);
    }
    #pragma unroll
    for (int it = 0; it < 4; ++it) {
        const int row = it * 8 + (t >> 5);
        union { bf16x8 v; unsigned u[4]; } af;
        af.u[0] = pk2(La[it][0].x, La[it][0].y);
        af.u[1] = pk2(La[it][0].z, La[it][0].w);
        af.u[2] = pk2(La[it][1].x, La[it][1].y);
        af.u[3] = pk2(La[it][1].z, La[it][1].w);
        const int us = row * 256 + (((kc * 2) ^ ((row & 7) << 4)) >> 1);
        *(bf16x8*)&As[us] = af.v;
    }
    __syncthreads();

    // ---- compute: acc[strip][cf], fully unrolled (static indexing) ----
    const int lrow = lane & 15;    // A row / B col / D col within 16
    const int lkb  = lane >> 4;    // k sub-block (8 elems each)
    const int colbase = w * 64;
    const int ct0 = colbase >> 4;

    f32x4 acc[2][4];
    #pragma unroll
    for (int s = 0; s < 2; ++s)
        #pragma unroll
        for (int c = 0; c < 4; ++c)
            acc[s][c] = (f32x4){0.f, 0.f, 0.f, 0.f};

    #pragma unroll
    for (int kb = 0; kb < 8; ++kb) {
        // B-fragments: coalesced 1 KB loads from fragment-order table (L2-hot)
        bf16x8 Bf0 = *(const bf16x8*)&encfrag[(((ct0 + 0) * 8 + kb) * 64 + lane) * 8];
        bf16x8 Bf1 = *(const bf16x8*)&encfrag[(((ct0 + 1) * 8 + kb) * 64 + lane) * 8];
        bf16x8 Bf2 = *(const bf16x8*)&encfrag[(((ct0 + 2) * 8 + kb) * 64 + lane) * 8];
        bf16x8 Bf3 = *(const bf16x8*)&encfrag[(((ct0 + 3) * 8 + kb) * 64 + lane) * 8];

        #pragma unroll
        for (int s = 0; s < 2; ++s) {
            const int row = s * 16 + lrow;
            const int kbyte = (kb * 64 + lkb * 16) ^ ((lrow & 7) << 4);
            const bf16x8 a = *(const bf16x8*)&As[row * 256 + (kbyte >> 1)];
            acc[s][0] = __builtin_amdgcn_mfma_f32_16x16x32_bf16(a, Bf0, acc[s][0], 0, 0, 0);
            acc[s][1] = __builtin_amdgcn_mfma_f32_16x16x32_bf16(a, Bf1, acc[s][1], 0, 0, 0);
            acc[s][2] = __builtin_amdgcn_mfma_f32_16x16x32_bf16(a, Bf2, acc[s][2], 0, 0, 0);
            acc[s][3] = __builtin_amdgcn_mfma_f32_16x16x32_bf16(a, Bf3, acc[s][3], 0, 0, 0);
        }
    }

    // ---- epilogue: D col = lane&15, row = lkb*4 + j (m89/R6-verified) ----
    #pragma unroll
    for (int s = 0; s < 2; ++s) {
        const int srow = r0 + s * 16 + lkb * 4;
        #pragma unroll
        for (int j = 0; j < 4; ++j) {
            const int rr = srow + j;
            if (rr < RELV) {
                ushort* pr = P2 + (size_t)rr * B + colbase + lrow;
                pr[0]  = f2bf(acc[s][0][j]);
                pr[16] = f2bf(acc[s][1][j]);
                pr[32] = f2bf(acc[s][2][j]);
                pr[48] = f2bf(acc[s][3][j]);
            }
        }
    }
}

// ---- kernel 3: ragged gather of precomputed scores (grid B*K/256) ----
__global__ __launch_bounds__(256)
void gather_out(const int* __restrict__ actions,
                const int* __restrict__ action_keys,
                const ushort* __restrict__ P2,
                float* __restrict__ out)
{
    const int tid = blockIdx.x * 256 + threadIdx.x;   // tid = b*K + k
    const int b   = tid >> 9;                         // K == 512
    const int r   = actions[action_keys[tid]];
    const unsigned bits = ((unsigned)P2[(size_t)r * B + b]) << 16;
    out[tid] = __uint_as_float(bits);
}

// ---- fallback (proven R2 kernel) if ws too small for P2 ----
#define CHUNKS 8
#define KPB (K / CHUNKS)
#define KPW (KPB / 4)
#define KPG (KPW / 4)

__global__ __launch_bounds__(256)
void preds_fused_kernel(const int* __restrict__ entities,
                        const int* __restrict__ actions,
                        const int* __restrict__ action_keys,
                        const float* __restrict__ encoded,
                        const float* __restrict__ rel_emb,
                        float* __restrict__ out)
{
    const int blk   = blockIdx.x;
    const int b     = blk >> 3;
    const int chunk = blk & 7;
    const int t     = threadIdx.x;
    const int lane  = t & 63;
    const int wave  = t >> 6;
    const int gid   = lane >> 4;
    const int gl    = lane & 15;

    __shared__ int s_count;
    if (t == 0) s_count = 0;
    __syncthreads();
    unsigned long long m0 = __ballot(entities[b * L + t] != 0);
    unsigned long long m1 = __ballot(entities[b * L + t + 256] != 0);
    if (lane == 0) atomicAdd(&s_count, __popcll(m0) + __popcll(m1));
    __syncthreads();
    int idx = s_count - 1;
    idx = max(0, min(L - 1, idx));

    const int kw = chunk * KPB + wave * KPW;
    const int* ak = action_keys + b * K;
    int av = 0;
    if (lane < KPW) av = actions[ak[kw + lane]];

    const float* encrow = &encoded[((size_t)(b * L + idx)) * H];
    const float4 e0 = *(const float4*)&encrow[gl * 4];
    const float4 e1 = *(const float4*)&encrow[gl * 4 + 64];
    const float4 e2 = *(const float4*)&encrow[gl * 4 + 128];
    const float4 e3 = *(const float4*)&encrow[gl * 4 + 192];

    #pragma unroll
    for (int i = 0; i < KPG; i += 2) {
        const int o0 = gid * KPG + i;
        const int o1 = o0 + 1;
        const int a0 = __shfl(av, o0, 64);
        const int a1 = __shfl(av, o1, 64);
        const float* r0 = &rel_emb[(size_t)a0 * H];
        const float* r1 = &rel_emb[(size_t)a1 * H];

        float4 r00 = *(const float4*)&r0[gl * 4];
        float4 r01 = *(const float4*)&r0[gl * 4 + 64];
        float4 r02 = *(const float4*)&r0[gl * 4 + 128];
        float4 r03 = *(const float4*)&r0[gl * 4 + 192];
        float4 r10 = *(const float4*)&r1[gl * 4];
        float4 r11 = *(const float4*)&r1[gl * 4 + 64];
        float4 r12 = *(const float4*)&r1[gl * 4 + 128];
        float4 r13 = *(const float4*)&r1[gl * 4 + 192];

        float p0 = r00.x * e0.x + r00.y * e0.y + r00.z * e0.z + r00.w * e0.w;
        p0 += r01.x * e1.x + r01.y * e1.y + r01.z * e1.z + r01.w * e1.w;
        p0 += r02.x * e2.x + r02.y * e2.y + r02.z * e2.z + r02.w * e2.w;
        p0 += r03.x * e3.x + r03.y * e3.y + r03.z * e3.z + r03.w * e3.w;
        float p1 = r10.x * e0.x + r10.y * e0.y + r10.z * e0.z + r10.w * e0.w;
        p1 += r11.x * e1.x + r11.y * e1.y + r11.z * e1.z + r11.w * e1.w;
        p1 += r12.x * e2.x + r12.y * e2.y + r12.z * e2.z + r12.w * e2.w;
        p1 += r13.x * e3.x + r13.y * e3.y + r13.z * e3.z + r13.w * e3.w;

        #pragma unroll
        for (int off = 1; off < 16; off <<= 1) {
            p0 += __shfl_xor(p0, off, 64);
            p1 += __shfl_xor(p1, off, 64);
        }
        if (gl == 0) {
            out[b * K + kw + o0] = p0;
            out[b * K + kw + o1] = p1;
        }
    }
}

extern "C" void kernel_launch(void* const* d_in, const int* in_sizes, int n_in,
                              void* d_out, int out_size, void* d_ws, size_t ws_size,
                              hipStream_t stream)
{
    const int*   entities    = (const int*)d_in[0];
    // d_in[1] = relations (unused by the reference computation)
    const int*   actions     = (const int*)d_in[2];
    const int*   action_keys = (const int*)d_in[3];
    const float* encoded     = (const float*)d_in[4];
    const float* rel_emb     = (const float*)d_in[5];
    float*       out         = (float*)d_out;

    if (ws_size >= WS_NEEDED) {
        ushort* encfrag = (ushort*)((char*)d_ws + WS_ENC_OFF);
        ushort* P2      = (ushort*)((char*)d_ws + WS_P2_OFF);

        hipLaunchKernelGGL(enc_cast, dim3(B), dim3(256), 0, stream,
                           entities, encoded, encfrag);
        hipLaunchKernelGGL(gemm_p2, dim3((RELV + BM - 1) / BM), dim3(256), 0, stream,
                           rel_emb, encfrag, P2);
        hipLaunchKernelGGL(gather_out, dim3(B * K / 256), dim3(256), 0, stream,
                           actions, action_keys, P2, out);
    } else {
        hipLaunchKernelGGL(preds_fused_kernel, dim3(B * CHUNKS), dim3(256), 0, stream,
                           entities, actions, action_keys, encoded, rel_emb, out);
    }
}